// Round 6
// baseline (302.703 us; speedup 1.0000x reference)
//
#include <hip/hip_runtime.h>
#include <hip/hip_bf16.h>
#include <math.h>

// Problem constants
#define BATCH 64
#define K1 50
#define K2 25
#define K3 12
#define N1 (K1*K1)        // 2500
#define N2 (K2*K2)        // 625
#define N3 (K3*K3)        // 144
#define EPS_IN 1e-5f

#define IRT2 0.70710678118654752f
#define IRT3 0.57735026918962576f

typedef __bf16 bf16x4 __attribute__((ext_vector_type(4)));
typedef __bf16 bf16x8 __attribute__((ext_vector_type(8)));
typedef float  f32x4  __attribute__((ext_vector_type(4)));

__device__ __forceinline__ float celu1(float v) {
    return v > 0.f ? v : (__expf(v) - 1.0f);
}

__device__ __forceinline__ float bfac(int v, int K) {
    return (v > 0 && v < K - 1) ? IRT3 : IRT2;
}

// ---------------------------------------------------------------------------
// Scalar 9-point symmetric-normalized stencil over [B, K1*K1] fields.
// Used twice: x -> agg, agg -> agg2.
// ---------------------------------------------------------------------------
__global__ __launch_bounds__(256) void stencil_kernel(
    const float* __restrict__ x, float* __restrict__ out)
{
    int node = blockIdx.x * 256 + threadIdx.x;   // 160000 exact
    int b = node / N1, n = node - b * N1;
    int i = n / K1, j = n - i * K1;

    float fi[3], fj[3];
    int ric[3], rjc[3];
    {
        int im = i - 1, ip = i + 1;
        ric[0] = im < 0 ? 0 : im;       fi[0] = im < 0 ? 0.f : bfac(im, K1);
        ric[1] = i;                     fi[1] = bfac(i, K1);
        ric[2] = ip >= K1 ? K1-1 : ip;  fi[2] = ip >= K1 ? 0.f : bfac(ip, K1);
        int jm = j - 1, jp = j + 1;
        rjc[0] = jm < 0 ? 0 : jm;       fj[0] = jm < 0 ? 0.f : bfac(jm, K1);
        rjc[1] = j;                     fj[1] = bfac(j, K1);
        rjc[2] = jp >= K1 ? K1-1 : jp;  fj[2] = jp >= K1 ? 0.f : bfac(jp, K1);
    }
    float rsdn = fi[1] * fj[1];
    int rowb = b * N1;

    float s = 0.f;
#pragma unroll
    for (int di = 0; di < 3; ++di) {
        float wr = rsdn * fi[di];
        int rb = rowb + ric[di] * K1;
#pragma unroll
        for (int dj = 0; dj < 3; ++dj)
            s = fmaf(wr * fj[dj], x[rb + rjc[dj]], s);
    }
    out[node] = s;
}

// ---------------------------------------------------------------------------
// conv1: rank-1 input GCNConv + InstanceNorm + CELU, fragment-direct (no LDS).
// ---------------------------------------------------------------------------
template<int KK>
__global__ __launch_bounds__(256, 4) void conv1_kernel(
    const float* __restrict__ agg2,
    const float* __restrict__ winit, const float* __restrict__ binit,
    const float* __restrict__ Wm, const float* __restrict__ bias,
    __bf16* __restrict__ out)
{
    constexpr int NN = KK * KK;
    const int lane = threadIdx.x & 63;
    const int wv   = threadIdx.x >> 6;
    const int c15  = lane & 15, q = lane >> 4;

    bf16x8 bfrag[4][2];
#pragma unroll
    for (int nt = 0; nt < 4; ++nt)
#pragma unroll
        for (int kf = 0; kf < 2; ++kf) {
            bf16x8 v;
#pragma unroll
            for (int jj = 0; jj < 8; ++jj)
                v[jj] = (__bf16)Wm[(kf * 32 + q * 8 + jj) * 64 + nt * 16 + c15];
            bfrag[nt][kf] = v;
        }
    float bias_l[4];
#pragma unroll
    for (int nt = 0; nt < 4; ++nt) bias_l[nt] = bias[nt * 16 + c15];

    float wik[2][8], bik[2][8];
#pragma unroll
    for (int kf = 0; kf < 2; ++kf)
#pragma unroll
        for (int jj = 0; jj < 8; ++jj) {
            wik[kf][jj] = winit[kf * 32 + q * 8 + jj];
            bik[kf][jj] = binit[kf * 32 + q * 8 + jj];
        }

    int node0 = blockIdx.x * 128 + wv * 32 + c15;

    f32x4 acc[2][4];
#pragma unroll
    for (int t = 0; t < 2; ++t)
#pragma unroll
        for (int nt = 0; nt < 4; ++nt)
            acc[t][nt] = (f32x4){0.f, 0.f, 0.f, 0.f};

#pragma unroll
    for (int tile = 0; tile < 2; ++tile) {
        int node = node0 + tile * 16;
        float a2 = agg2[node];
        int b = node / NN, n = node - b * NN;
        int i = n / KK, j = n - i * KK;
        float f1i = bfac(i, KK), f1j = bfac(j, KK);
        float si = f1i + ((i > 0) ? bfac(i - 1, KK) : 0.f) + ((i < KK-1) ? bfac(i + 1, KK) : 0.f);
        float sj = f1j + ((j > 0) ? bfac(j - 1, KK) : 0.f) + ((j < KK-1) ? bfac(j + 1, KK) : 0.f);
        float tt = f1i * f1j * si * sj;

        bf16x8 av0, av1;
#pragma unroll
        for (int jj = 0; jj < 8; ++jj) {
            av0[jj] = (__bf16)fmaf(a2, wik[0][jj], tt * bik[0][jj]);
            av1[jj] = (__bf16)fmaf(a2, wik[1][jj], tt * bik[1][jj]);
        }
#pragma unroll
        for (int nt = 0; nt < 4; ++nt) {
            acc[tile][nt] = __builtin_amdgcn_mfma_f32_16x16x32_bf16(av0, bfrag[nt][0], acc[tile][nt], 0, 0, 0);
            acc[tile][nt] = __builtin_amdgcn_mfma_f32_16x16x32_bf16(av1, bfrag[nt][1], acc[tile][nt], 0, 0, 0);
        }
    }

#pragma unroll
    for (int tile = 0; tile < 2; ++tile) {
        float tm[4][4];
#pragma unroll
        for (int nt = 0; nt < 4; ++nt)
#pragma unroll
            for (int r = 0; r < 4; ++r)
                tm[nt][r] = acc[tile][nt][r] + bias_l[nt];

#pragma unroll
        for (int r = 0; r < 4; ++r) {
            float p = tm[0][r] + tm[1][r] + tm[2][r] + tm[3][r];
#pragma unroll
            for (int off = 1; off < 16; off <<= 1) p += __shfl_xor(p, off, 64);
            float mean = p * (1.0f / 64.0f);
            float vs = 0.f;
#pragma unroll
            for (int nt = 0; nt < 4; ++nt) {
                float d = tm[nt][r] - mean;
                vs = fmaf(d, d, vs);
            }
#pragma unroll
            for (int off = 1; off < 16; off <<= 1) vs += __shfl_xor(vs, off, 64);
            float rstd = __frsqrt_rn(vs * (1.0f / 64.0f) + EPS_IN);

            int node = blockIdx.x * 128 + wv * 32 + tile * 16 + q * 4 + r;
            int base = node * 64 + c15;
#pragma unroll
            for (int nt = 0; nt < 4; ++nt)
                out[base + nt * 16] = (__bf16)celu1((tm[nt][r] - mean) * rstd);
        }
    }
}

// ---------------------------------------------------------------------------
// General fused GCNConv (MFMA) + InstanceNorm + residual + CELU.
// Phase A: lane = (node-eighth, 8 channels), bf16x8 16B loads, 4 m-iters.
// ---------------------------------------------------------------------------
template<int KK, int MODE, bool BOUND>
__global__ __launch_bounds__(256, 4) void conv_kernel(
    const __bf16* __restrict__ xin, const __bf16* __restrict__ auxv,
    const float* __restrict__ auxs,
    const float* __restrict__ winit, const float* __restrict__ binit,
    const float* __restrict__ Wm, const float* __restrict__ bias,
    __bf16* __restrict__ out, int Ntot)
{
    constexpr int NN = KK * KK;
    __shared__ __align__(16) __bf16 s_lds[128 * 72];

    const int lane = threadIdx.x & 63;
    const int wv   = threadIdx.x >> 6;
    const int c15  = lane & 15, q = lane >> 4;
    const int n8   = lane >> 3;          // node-eighth in phase A
    const int ch8  = (lane & 7) * 8;     // 8-channel group in phase A

    bf16x8 bfrag[4][2];
#pragma unroll
    for (int nt = 0; nt < 4; ++nt)
#pragma unroll
        for (int kf = 0; kf < 2; ++kf) {
            bf16x8 v;
#pragma unroll
            for (int jj = 0; jj < 8; ++jj)
                v[jj] = (__bf16)Wm[(kf * 32 + q * 8 + jj) * 64 + nt * 16 + c15];
            bfrag[nt][kf] = v;
        }
    float bias_l[4];
#pragma unroll
    for (int nt = 0; nt < 4; ++nt) bias_l[nt] = bias[nt * 16 + c15];

    float wi_e[4], bi_e[4];
    if (MODE == 3) {
#pragma unroll
        for (int nt = 0; nt < 4; ++nt) {
            wi_e[nt] = winit[nt * 16 + c15];
            bi_e[nt] = binit[nt * 16 + c15];
        }
    }

    const int G0 = blockIdx.x * 128;

    // ---- phase A: stencil aggregate, 8 nodes per wave-instr, 16B loads ----
#pragma unroll 2
    for (int m = 0; m < 4; ++m) {
        int nl = wv * 32 + m * 8 + n8;
        int node = G0 + nl;
        if (BOUND) node = min(node, Ntot - 1);
        int b = node / NN, n = node - b * NN;
        int i = n / KK, j = n - i * KK;

        float fi[3], fj[3];
        int ric[3], rjc[3];
        {
            int im = i - 1, ip = i + 1;
            ric[0] = im < 0 ? 0 : im;       fi[0] = im < 0 ? 0.f : bfac(im, KK);
            ric[1] = i;                     fi[1] = bfac(i, KK);
            ric[2] = ip >= KK ? KK-1 : ip;  fi[2] = ip >= KK ? 0.f : bfac(ip, KK);
            int jm = j - 1, jp = j + 1;
            rjc[0] = jm < 0 ? 0 : jm;       fj[0] = jm < 0 ? 0.f : bfac(jm, KK);
            rjc[1] = j;                     fj[1] = bfac(j, KK);
            rjc[2] = jp >= KK ? KK-1 : jp;  fj[2] = jp >= KK ? 0.f : bfac(jp, KK);
        }
        float rsdn = fi[1] * fj[1];

        int rbase[3], coff[3];
#pragma unroll
        for (int t = 0; t < 3; ++t) rbase[t] = (b * NN + ric[t] * KK) * 64 + ch8;
#pragma unroll
        for (int t = 0; t < 3; ++t) coff[t] = rjc[t] * 64;

        float s[8];
#pragma unroll
        for (int z = 0; z < 8; ++z) s[z] = 0.f;
#pragma unroll
        for (int di = 0; di < 3; ++di) {
            float wr = rsdn * fi[di];
#pragma unroll
            for (int dj = 0; dj < 3; ++dj) {
                float wgt = wr * fj[dj];
                bf16x8 v = *(const bf16x8*)(xin + rbase[di] + coff[dj]);
#pragma unroll
                for (int z = 0; z < 8; ++z)
                    s[z] = fmaf(wgt, (float)v[z], s[z]);
            }
        }
        bf16x8 sv;
#pragma unroll
        for (int z = 0; z < 8; ++z) sv[z] = (__bf16)s[z];
        *(bf16x8*)(s_lds + nl * 72 + ch8) = sv;
    }

    // ---- phase B: MFMA ----
    f32x4 acc[2][4];
#pragma unroll
    for (int t = 0; t < 2; ++t)
#pragma unroll
        for (int nt = 0; nt < 4; ++nt)
            acc[t][nt] = (f32x4){0.f, 0.f, 0.f, 0.f};

#pragma unroll
    for (int tile = 0; tile < 2; ++tile) {
        int r0 = wv * 32 + tile * 16 + c15;
        bf16x8 av0 = *(const bf16x8*)(s_lds + r0 * 72 + q * 8);
        bf16x8 av1 = *(const bf16x8*)(s_lds + r0 * 72 + 32 + q * 8);
#pragma unroll
        for (int nt = 0; nt < 4; ++nt) {
            acc[tile][nt] = __builtin_amdgcn_mfma_f32_16x16x32_bf16(av0, bfrag[nt][0], acc[tile][nt], 0, 0, 0);
            acc[tile][nt] = __builtin_amdgcn_mfma_f32_16x16x32_bf16(av1, bfrag[nt][1], acc[tile][nt], 0, 0, 0);
        }
    }

    // ---- epilogue ----
#pragma unroll
    for (int tile = 0; tile < 2; ++tile) {
        float tm[4][4];
#pragma unroll
        for (int nt = 0; nt < 4; ++nt)
#pragma unroll
            for (int r = 0; r < 4; ++r)
                tm[nt][r] = acc[tile][nt][r] + bias_l[nt];

#pragma unroll
        for (int r = 0; r < 4; ++r) {
            float p = tm[0][r] + tm[1][r] + tm[2][r] + tm[3][r];
#pragma unroll
            for (int off = 1; off < 16; off <<= 1) p += __shfl_xor(p, off, 64);
            float mean = p * (1.0f / 64.0f);
            float vs = 0.f;
#pragma unroll
            for (int nt = 0; nt < 4; ++nt) {
                float d = tm[nt][r] - mean;
                vs = fmaf(d, d, vs);
            }
#pragma unroll
            for (int off = 1; off < 16; off <<= 1) vs += __shfl_xor(vs, off, 64);
            float rstd = __frsqrt_rn(vs * (1.0f / 64.0f) + EPS_IN);

            int node = G0 + wv * 32 + tile * 16 + q * 4 + r;
            if (!BOUND || node < Ntot) {
                int base = node * 64 + c15;
                float av = 0.f;
                if (MODE == 3) av = auxs[node];
#pragma unroll
                for (int nt = 0; nt < 4; ++nt) {
                    float d = (tm[nt][r] - mean) * rstd;
                    if (MODE == 1) d += (float)auxv[base + nt * 16];
                    if (MODE == 3) d = fmaf(av, wi_e[nt], d + bi_e[nt]);
                    out[base + nt * 16] = (__bf16)celu1(d);
                }
            }
        }
    }
}

// ---------------------------------------------------------------------------
// 2x2 max pool (truncating), bf16 in/out, 4 channels per lane
// ---------------------------------------------------------------------------
template<int KK>
__global__ __launch_bounds__(256) void pool_kernel(
    const __bf16* __restrict__ xin, __bf16* __restrict__ out)
{
    constexpr int NIN = KK * KK;
    constexpr int KH = KK / 2;
    constexpr int P = KH * KH;
    int e = blockIdx.x * 256 + threadIdx.x;
    int c = (e & 15) * 4;
    int np = e >> 4;
    int b = np / P, p = np - b * P;
    int pi = p / KH, pj = p - pi * KH;
    int basei = (b * NIN + (2 * pi) * KK + 2 * pj) * 64 + c;
    bf16x4 v0 = *(const bf16x4*)(xin + basei);
    bf16x4 v1 = *(const bf16x4*)(xin + basei + 64);
    bf16x4 v2 = *(const bf16x4*)(xin + basei + KK * 64);
    bf16x4 v3 = *(const bf16x4*)(xin + basei + KK * 64 + 64);
    bf16x4 o;
#pragma unroll
    for (int z = 0; z < 4; ++z) {
        float mv = fmaxf(fmaxf((float)v0[z], (float)v1[z]),
                         fmaxf((float)v2[z], (float)v3[z]));
        o[z] = (__bf16)mv;
    }
    *(bf16x4*)(out + np * 64 + c) = o;
}

// ---------------------------------------------------------------------------
// Merged partial Gram: z<6 -> W1 chunk z; z>=6 -> W2 chunk z-6.
// ---------------------------------------------------------------------------
__global__ __launch_bounds__(256) void gram_kernel(
    const float* __restrict__ W1, const float* __restrict__ W2,
    float* __restrict__ Gp1, float* __restrict__ Gp2)
{
    const float* W; float* G; int K, kc, s;
    if (blockIdx.z < 6) { W = W1; K = 2304; kc = 384; s = blockIdx.z;     G = Gp1 + s * 65536; }
    else               { W = W2; K = 256;  kc = 128; s = blockIdx.z - 6; G = Gp2 + s * 65536; }

    __shared__ float As[32][33];
    __shared__ float Bs[32][33];
    int ti = blockIdx.x * 32;
    int tj = blockIdx.y * 32;
    int k0s = s * kc;
    int tx = threadIdx.x & 15, ty = threadIdx.x >> 4;
    float a00 = 0.f, a01 = 0.f, a10 = 0.f, a11 = 0.f;
    for (int k0 = k0s; k0 < k0s + kc; k0 += 32) {
        for (int l = threadIdx.x; l < 1024; l += 256) {
            int r = l >> 5, cc = l & 31;
            As[r][cc] = W[(ti + r) * K + k0 + cc];
            Bs[r][cc] = W[(tj + r) * K + k0 + cc];
        }
        __syncthreads();
#pragma unroll
        for (int kk = 0; kk < 32; ++kk) {
            float a0 = As[ty][kk],      a1 = As[ty + 16][kk];
            float b0 = Bs[tx][kk],      b1 = Bs[tx + 16][kk];
            a00 = fmaf(a0, b0, a00); a01 = fmaf(a0, b1, a01);
            a10 = fmaf(a1, b0, a10); a11 = fmaf(a1, b1, a11);
        }
        __syncthreads();
    }
    G[(ti + ty) * 256 + tj + tx]           = a00;
    G[(ti + ty) * 256 + tj + tx + 16]      = a01;
    G[(ti + ty + 16) * 256 + tj + tx]      = a10;
    G[(ti + ty + 16) * 256 + tj + tx + 16] = a11;
}

// ---------------------------------------------------------------------------
// Power iteration on symmetric G (256x256), partial-sum G inputs, deferred
// normalization. g[64] pinned in VGPRs; u read via ds_read_b128.
// ---------------------------------------------------------------------------
__global__ __launch_bounds__(1024, 4) void power_kernel(
    const float* __restrict__ Gp1, const float* __restrict__ Gp2,
    float* __restrict__ sig)
{
    const float* Gp = (blockIdx.x == 0) ? Gp1 : Gp2;
    const int S = (blockIdx.x == 0) ? 6 : 2;
    __shared__ __align__(16) float u[256];
    __shared__ float red[1024];
    __shared__ float gu_s[256];
    int tid = threadIdx.x, i = tid & 255, q = tid >> 8;

    float g[64];
#pragma unroll
    for (int m = 0; m < 64; ++m) g[m] = 0.f;
    for (int s = 0; s < S; ++s) {
        const float* Gs = Gp + s * 65536;
#pragma unroll
        for (int m = 0; m < 64; ++m)
            g[m] += Gs[(q * 64 + m) * 256 + i];
    }
    // pin: prevent scratch demotion of the accumulator array
#pragma unroll
    for (int m = 0; m < 64; ++m) asm volatile("" : "+v"(g[m]));

    if (tid < 256) u[tid] = 0.0625f;
    __syncthreads();

    for (int it = 0; it < 29; ++it) {
        float p = 0.f;
#pragma unroll
        for (int m4 = 0; m4 < 16; ++m4) {
            f32x4 uv = *(const f32x4*)(u + q * 64 + m4 * 4);
            p = fmaf(g[m4 * 4 + 0], uv[0], p);
            p = fmaf(g[m4 * 4 + 1], uv[1], p);
            p = fmaf(g[m4 * 4 + 2], uv[2], p);
            p = fmaf(g[m4 * 4 + 3], uv[3], p);
        }
        red[tid] = p;
        __syncthreads();
        if (tid < 256)
            u[tid] = (red[tid] + red[tid + 256] + red[tid + 512] + red[tid + 768]) * 0.5f;
        __syncthreads();
    }

    float p = 0.f;
#pragma unroll
    for (int m4 = 0; m4 < 16; ++m4) {
        f32x4 uv = *(const f32x4*)(u + q * 64 + m4 * 4);
        p = fmaf(g[m4 * 4 + 0], uv[0], p);
        p = fmaf(g[m4 * 4 + 1], uv[1], p);
        p = fmaf(g[m4 * 4 + 2], uv[2], p);
        p = fmaf(g[m4 * 4 + 3], uv[3], p);
    }
    red[tid] = p;
    __syncthreads();
    if (tid < 256)
        gu_s[tid] = red[tid] + red[tid + 256] + red[tid + 512] + red[tid + 768];
    __syncthreads();
    if (tid < 64) {
        float a = 0.f, bs = 0.f;
        for (int z = tid; z < 256; z += 64) {
            float v = gu_s[z];
            a = fmaf(v, v, a);
            bs = fmaf(u[z], v, bs);
        }
#pragma unroll
        for (int off = 32; off; off >>= 1) {
            a  += __shfl_xor(a, off, 64);
            bs += __shfl_xor(bs, off, 64);
        }
        if (tid == 0) sig[blockIdx.x] = sqrtf(a / bs);
    }
}

// ---------------------------------------------------------------------------
// Split-K linear partials (X is bf16) + epilogue
// ---------------------------------------------------------------------------
__global__ __launch_bounds__(256) void linear_part(
    const __bf16* __restrict__ X, const float* __restrict__ Wt,
    float* __restrict__ part, int K, int kchunk)
{
    __shared__ float wl[64 * 129];
    __shared__ float hl[16 * 128];
    int o0 = blockIdx.x * 64, b0 = blockIdx.y * 16;
    int s = blockIdx.z;
    int k0s = s * kchunk;
    int t = threadIdx.x, o = t & 63, br = t >> 6;
    float acc[4] = {0.f, 0.f, 0.f, 0.f};

    for (int k0 = k0s; k0 < k0s + kchunk; k0 += 128) {
        for (int l = t; l < 64 * 128; l += 256) {
            int r = l >> 7, cc = l & 127;
            wl[r * 129 + cc] = Wt[(o0 + r) * K + k0 + cc];
        }
        for (int l = t; l < 16 * 128; l += 256) {
            int r = l >> 7, cc = l & 127;
            hl[r * 128 + cc] = (float)X[(b0 + r) * K + k0 + cc];
        }
        __syncthreads();
        for (int kk = 0; kk < 128; ++kk) {
            float wv = wl[o * 129 + kk];
#pragma unroll
            for (int r = 0; r < 4; ++r)
                acc[r] = fmaf(hl[(br + (r << 2)) * 128 + kk], wv, acc[r]);
        }
        __syncthreads();
    }
#pragma unroll
    for (int r = 0; r < 4; ++r)
        part[(s * 64 + b0 + br + (r << 2)) * 256 + o0 + o] = acc[r];
}

__global__ __launch_bounds__(256) void linear_epi(
    const float* __restrict__ part, const float* __restrict__ bias,
    const float* __restrict__ sig, int sidx, int S,
    float* __restrict__ outf, __bf16* __restrict__ outb)
{
    int idx = blockIdx.x * 256 + threadIdx.x;
    float a = 0.f;
    for (int s = 0; s < S; ++s) a += part[s * 16384 + idx];
    int o = idx & 255;
    float v = celu1(a / sig[sidx] + bias[o]);
    if (outf) outf[idx] = v;
    if (outb) outb[idx] = (__bf16)v;
}

// ---------------------------------------------------------------------------
extern "C" void kernel_launch(void* const* d_in, const int* in_sizes, int n_in,
                              void* d_out, int out_size, void* d_ws, size_t ws_size,
                              hipStream_t stream)
{
    const float* x      = (const float*)d_in[0];
    const float* w_init = (const float*)d_in[1];
    const float* b_init = (const float*)d_in[2];
    const float* w11 = (const float*)d_in[3];  const float* b11 = (const float*)d_in[4];
    const float* w12 = (const float*)d_in[5];  const float* b12 = (const float*)d_in[6];
    const float* w21 = (const float*)d_in[7];  const float* b21 = (const float*)d_in[8];
    const float* w22 = (const float*)d_in[9];  const float* b22 = (const float*)d_in[10];
    const float* w31 = (const float*)d_in[11]; const float* b31 = (const float*)d_in[12];
    const float* w32 = (const float*)d_in[13]; const float* b32 = (const float*)d_in[14];
    const float* lw1 = (const float*)d_in[15]; const float* lb1 = (const float*)d_in[16];
    const float* lw2 = (const float*)d_in[17]; const float* lb2 = (const float*)d_in[18];
    float* out = (float*)d_out;

    char* ws = (char*)d_ws;
    const size_t SZ_BIG = (size_t)BATCH * N1 * 64 * sizeof(float);   // 40,960,000 B
    __bf16* A    = (__bf16*)ws;
    __bf16* Bb   = (__bf16*)(ws + SZ_BIG);
    __bf16* Cb   = (__bf16*)(ws + 2 * SZ_BIG);
    float*  agg  = (float*)(ws + 3 * SZ_BIG);          // 640 KB
    float*  agg2 = agg + BATCH * N1;                   // 640 KB
    float* Gp1   = agg2 + BATCH * N1;    // 6 * 65536
    float* Gp2   = Gp1 + 6 * 65536;      // 2 * 65536
    float* sg    = Gp2 + 2 * 65536;      // 2 (+pad)
    float* part1 = sg + 16;              // 6 * 16384
    float* part2 = part1 + 6 * 16384;    // 2 * 16384
    __bf16* H1b  = (__bf16*)(part2 + 2 * 16384);   // 16384 bf16

    // Stage 0: scalar aggregate fields (h0 rank-1, never materialized)
    stencil_kernel<<<625, 256, 0, stream>>>(x, agg);
    stencil_kernel<<<625, 256, 0, stream>>>(agg, agg2);

    // Block 1 (k=50, 160000 nodes, exact grids)
    conv1_kernel<K1><<<1250, 256, 0, stream>>>(agg2, w_init, b_init, w11, b11, Bb);
    conv_kernel<K1, 3, false><<<1250, 256, 0, stream>>>(Bb, nullptr, agg, w_init, b_init, w12, b12, Cb, BATCH * N1);
    pool_kernel<K1><<<BATCH * N2 * 16 / 256, 256, 0, stream>>>(Cb, A);

    // Block 2 (k=25, 40000 nodes)
    conv_kernel<K2, 0, true><<<313, 256, 0, stream>>>(A,  nullptr, nullptr, nullptr, nullptr, w21, b21, Bb, BATCH * N2);
    conv_kernel<K2, 1, true><<<313, 256, 0, stream>>>(Bb, A,       nullptr, nullptr, nullptr, w22, b22, Cb, BATCH * N2);
    pool_kernel<K2><<<BATCH * N3 * 16 / 256, 256, 0, stream>>>(Cb, A);

    // Block 3 (k=12, 9216 nodes, exact)
    conv_kernel<K3, 0, false><<<72, 256, 0, stream>>>(A,  nullptr, nullptr, nullptr, nullptr, w31, b31, Bb, BATCH * N3);
    conv_kernel<K3, 1, false><<<72, 256, 0, stream>>>(Bb, A,       nullptr, nullptr, nullptr, w32, b32, Cb, BATCH * N3);
    pool_kernel<K3><<<BATCH * 36 * 16 / 256, 256, 0, stream>>>(Cb, A);
    // A now holds h [64, 36, 64] bf16 == flattened [64, 2304]

    // Spectral norms (gram partials; reduce folded into power)
    gram_kernel<<<dim3(8, 8, 8), 256, 0, stream>>>(lw1, lw2, Gp1, Gp2);
    power_kernel<<<2, 1024, 0, stream>>>(Gp1, Gp2, sg);

    // Final linears with CELU (split-K partials + epilogue)
    linear_part<<<dim3(4, 4, 6), 256, 0, stream>>>(A,   lw1, part1, 2304, 384);
    linear_epi<<<64, 256, 0, stream>>>(part1, lb1, sg, 0, 6, nullptr, H1b);
    linear_part<<<dim3(4, 4, 2), 256, 0, stream>>>(H1b, lw2, part2, 256, 128);
    linear_epi<<<64, 256, 0, stream>>>(part2, lb2, sg, 1, 2, out, nullptr);
}

// Round 7
// 295.353 us; speedup vs baseline: 1.0249x; 1.0249x over previous
//
#include <hip/hip_runtime.h>
#include <hip/hip_bf16.h>
#include <math.h>

// Problem constants
#define BATCH 64
#define K1 50
#define K2 25
#define K3 12
#define N1 (K1*K1)        // 2500
#define N2 (K2*K2)        // 625
#define N3 (K3*K3)        // 144
#define EPS_IN 1e-5f

#define IRT2 0.70710678118654752f
#define IRT3 0.57735026918962576f

typedef __bf16 bf16x4 __attribute__((ext_vector_type(4)));
typedef __bf16 bf16x8 __attribute__((ext_vector_type(8)));
typedef float  f32x4  __attribute__((ext_vector_type(4)));

__device__ __forceinline__ float celu1(float v) {
    return v > 0.f ? v : (__expf(v) - 1.0f);
}

__device__ __forceinline__ float bfac(int v, int K) {
    return (v > 0 && v < K - 1) ? IRT3 : IRT2;
}

// ---------------------------------------------------------------------------
// Scalar 9-point symmetric-normalized stencil over [B, K1*K1] fields.
// Used twice: x -> agg, agg -> agg2.
// ---------------------------------------------------------------------------
__global__ __launch_bounds__(256) void stencil_kernel(
    const float* __restrict__ x, float* __restrict__ out)
{
    int node = blockIdx.x * 256 + threadIdx.x;   // 160000 exact
    int b = node / N1, n = node - b * N1;
    int i = n / K1, j = n - i * K1;

    float fi[3], fj[3];
    int ric[3], rjc[3];
    {
        int im = i - 1, ip = i + 1;
        ric[0] = im < 0 ? 0 : im;       fi[0] = im < 0 ? 0.f : bfac(im, K1);
        ric[1] = i;                     fi[1] = bfac(i, K1);
        ric[2] = ip >= K1 ? K1-1 : ip;  fi[2] = ip >= K1 ? 0.f : bfac(ip, K1);
        int jm = j - 1, jp = j + 1;
        rjc[0] = jm < 0 ? 0 : jm;       fj[0] = jm < 0 ? 0.f : bfac(jm, K1);
        rjc[1] = j;                     fj[1] = bfac(j, K1);
        rjc[2] = jp >= K1 ? K1-1 : jp;  fj[2] = jp >= K1 ? 0.f : bfac(jp, K1);
    }
    float rsdn = fi[1] * fj[1];
    int rowb = b * N1;

    float s = 0.f;
#pragma unroll
    for (int di = 0; di < 3; ++di) {
        float wr = rsdn * fi[di];
        int rb = rowb + ric[di] * K1;
#pragma unroll
        for (int dj = 0; dj < 3; ++dj)
            s = fmaf(wr * fj[dj], x[rb + rjc[dj]], s);
    }
    out[node] = s;
}

// ---------------------------------------------------------------------------
// conv1: rank-1 input GCNConv + InstanceNorm + CELU, fragment-direct (no LDS).
// ---------------------------------------------------------------------------
template<int KK>
__global__ __launch_bounds__(256, 4) void conv1_kernel(
    const float* __restrict__ agg2,
    const float* __restrict__ winit, const float* __restrict__ binit,
    const float* __restrict__ Wm, const float* __restrict__ bias,
    __bf16* __restrict__ out)
{
    constexpr int NN = KK * KK;
    const int lane = threadIdx.x & 63;
    const int wv   = threadIdx.x >> 6;
    const int c15  = lane & 15, q = lane >> 4;

    bf16x8 bfrag[4][2];
#pragma unroll
    for (int nt = 0; nt < 4; ++nt)
#pragma unroll
        for (int kf = 0; kf < 2; ++kf) {
            bf16x8 v;
#pragma unroll
            for (int jj = 0; jj < 8; ++jj)
                v[jj] = (__bf16)Wm[(kf * 32 + q * 8 + jj) * 64 + nt * 16 + c15];
            bfrag[nt][kf] = v;
        }
    float bias_l[4];
#pragma unroll
    for (int nt = 0; nt < 4; ++nt) bias_l[nt] = bias[nt * 16 + c15];

    float wik[2][8], bik[2][8];
#pragma unroll
    for (int kf = 0; kf < 2; ++kf)
#pragma unroll
        for (int jj = 0; jj < 8; ++jj) {
            wik[kf][jj] = winit[kf * 32 + q * 8 + jj];
            bik[kf][jj] = binit[kf * 32 + q * 8 + jj];
        }

    int node0 = blockIdx.x * 128 + wv * 32 + c15;

    f32x4 acc[2][4];
#pragma unroll
    for (int t = 0; t < 2; ++t)
#pragma unroll
        for (int nt = 0; nt < 4; ++nt)
            acc[t][nt] = (f32x4){0.f, 0.f, 0.f, 0.f};

#pragma unroll
    for (int tile = 0; tile < 2; ++tile) {
        int node = node0 + tile * 16;
        float a2 = agg2[node];
        int b = node / NN, n = node - b * NN;
        int i = n / KK, j = n - i * KK;
        float f1i = bfac(i, KK), f1j = bfac(j, KK);
        float si = f1i + ((i > 0) ? bfac(i - 1, KK) : 0.f) + ((i < KK-1) ? bfac(i + 1, KK) : 0.f);
        float sj = f1j + ((j > 0) ? bfac(j - 1, KK) : 0.f) + ((j < KK-1) ? bfac(j + 1, KK) : 0.f);
        float tt = f1i * f1j * si * sj;

        bf16x8 av0, av1;
#pragma unroll
        for (int jj = 0; jj < 8; ++jj) {
            av0[jj] = (__bf16)fmaf(a2, wik[0][jj], tt * bik[0][jj]);
            av1[jj] = (__bf16)fmaf(a2, wik[1][jj], tt * bik[1][jj]);
        }
#pragma unroll
        for (int nt = 0; nt < 4; ++nt) {
            acc[tile][nt] = __builtin_amdgcn_mfma_f32_16x16x32_bf16(av0, bfrag[nt][0], acc[tile][nt], 0, 0, 0);
            acc[tile][nt] = __builtin_amdgcn_mfma_f32_16x16x32_bf16(av1, bfrag[nt][1], acc[tile][nt], 0, 0, 0);
        }
    }

#pragma unroll
    for (int tile = 0; tile < 2; ++tile) {
        float tm[4][4];
#pragma unroll
        for (int nt = 0; nt < 4; ++nt)
#pragma unroll
            for (int r = 0; r < 4; ++r)
                tm[nt][r] = acc[tile][nt][r] + bias_l[nt];

#pragma unroll
        for (int r = 0; r < 4; ++r) {
            float p = tm[0][r] + tm[1][r] + tm[2][r] + tm[3][r];
#pragma unroll
            for (int off = 1; off < 16; off <<= 1) p += __shfl_xor(p, off, 64);
            float mean = p * (1.0f / 64.0f);
            float vs = 0.f;
#pragma unroll
            for (int nt = 0; nt < 4; ++nt) {
                float d = tm[nt][r] - mean;
                vs = fmaf(d, d, vs);
            }
#pragma unroll
            for (int off = 1; off < 16; off <<= 1) vs += __shfl_xor(vs, off, 64);
            float rstd = __frsqrt_rn(vs * (1.0f / 64.0f) + EPS_IN);

            int node = blockIdx.x * 128 + wv * 32 + tile * 16 + q * 4 + r;
            int base = node * 64 + c15;
#pragma unroll
            for (int nt = 0; nt < 4; ++nt)
                out[base + nt * 16] = (__bf16)celu1((tm[nt][r] - mean) * rstd);
        }
    }
}

// ---------------------------------------------------------------------------
// General fused GCNConv (MFMA) + InstanceNorm + residual + CELU.
// Phase A: lane = (node-eighth, 8 channels), bf16x8 16B loads, 4 m-iters.
// ---------------------------------------------------------------------------
template<int KK, int MODE, bool BOUND>
__global__ __launch_bounds__(256, 4) void conv_kernel(
    const __bf16* __restrict__ xin, const __bf16* __restrict__ auxv,
    const float* __restrict__ auxs,
    const float* __restrict__ winit, const float* __restrict__ binit,
    const float* __restrict__ Wm, const float* __restrict__ bias,
    __bf16* __restrict__ out, int Ntot)
{
    constexpr int NN = KK * KK;
    __shared__ __align__(16) __bf16 s_lds[128 * 72];

    const int lane = threadIdx.x & 63;
    const int wv   = threadIdx.x >> 6;
    const int c15  = lane & 15, q = lane >> 4;
    const int n8   = lane >> 3;          // node-eighth in phase A
    const int ch8  = (lane & 7) * 8;     // 8-channel group in phase A

    bf16x8 bfrag[4][2];
#pragma unroll
    for (int nt = 0; nt < 4; ++nt)
#pragma unroll
        for (int kf = 0; kf < 2; ++kf) {
            bf16x8 v;
#pragma unroll
            for (int jj = 0; jj < 8; ++jj)
                v[jj] = (__bf16)Wm[(kf * 32 + q * 8 + jj) * 64 + nt * 16 + c15];
            bfrag[nt][kf] = v;
        }
    float bias_l[4];
#pragma unroll
    for (int nt = 0; nt < 4; ++nt) bias_l[nt] = bias[nt * 16 + c15];

    float wi_e[4], bi_e[4];
    if (MODE == 3) {
#pragma unroll
        for (int nt = 0; nt < 4; ++nt) {
            wi_e[nt] = winit[nt * 16 + c15];
            bi_e[nt] = binit[nt * 16 + c15];
        }
    }

    const int G0 = blockIdx.x * 128;

    // ---- phase A: stencil aggregate, 8 nodes per wave-instr, 16B loads ----
#pragma unroll 2
    for (int m = 0; m < 4; ++m) {
        int nl = wv * 32 + m * 8 + n8;
        int node = G0 + nl;
        if (BOUND) node = min(node, Ntot - 1);
        int b = node / NN, n = node - b * NN;
        int i = n / KK, j = n - i * KK;

        float fi[3], fj[3];
        int ric[3], rjc[3];
        {
            int im = i - 1, ip = i + 1;
            ric[0] = im < 0 ? 0 : im;       fi[0] = im < 0 ? 0.f : bfac(im, KK);
            ric[1] = i;                     fi[1] = bfac(i, KK);
            ric[2] = ip >= KK ? KK-1 : ip;  fi[2] = ip >= KK ? 0.f : bfac(ip, KK);
            int jm = j - 1, jp = j + 1;
            rjc[0] = jm < 0 ? 0 : jm;       fj[0] = jm < 0 ? 0.f : bfac(jm, KK);
            rjc[1] = j;                     fj[1] = bfac(j, KK);
            rjc[2] = jp >= KK ? KK-1 : jp;  fj[2] = jp >= KK ? 0.f : bfac(jp, KK);
        }
        float rsdn = fi[1] * fj[1];

        int rbase[3], coff[3];
#pragma unroll
        for (int t = 0; t < 3; ++t) rbase[t] = (b * NN + ric[t] * KK) * 64 + ch8;
#pragma unroll
        for (int t = 0; t < 3; ++t) coff[t] = rjc[t] * 64;

        float s[8];
#pragma unroll
        for (int z = 0; z < 8; ++z) s[z] = 0.f;
#pragma unroll
        for (int di = 0; di < 3; ++di) {
            float wr = rsdn * fi[di];
#pragma unroll
            for (int dj = 0; dj < 3; ++dj) {
                float wgt = wr * fj[dj];
                bf16x8 v = *(const bf16x8*)(xin + rbase[di] + coff[dj]);
#pragma unroll
                for (int z = 0; z < 8; ++z)
                    s[z] = fmaf(wgt, (float)v[z], s[z]);
            }
        }
        bf16x8 sv;
#pragma unroll
        for (int z = 0; z < 8; ++z) sv[z] = (__bf16)s[z];
        *(bf16x8*)(s_lds + nl * 72 + ch8) = sv;
    }

    // ---- phase B: MFMA ----
    f32x4 acc[2][4];
#pragma unroll
    for (int t = 0; t < 2; ++t)
#pragma unroll
        for (int nt = 0; nt < 4; ++nt)
            acc[t][nt] = (f32x4){0.f, 0.f, 0.f, 0.f};

#pragma unroll
    for (int tile = 0; tile < 2; ++tile) {
        int r0 = wv * 32 + tile * 16 + c15;
        bf16x8 av0 = *(const bf16x8*)(s_lds + r0 * 72 + q * 8);
        bf16x8 av1 = *(const bf16x8*)(s_lds + r0 * 72 + 32 + q * 8);
#pragma unroll
        for (int nt = 0; nt < 4; ++nt) {
            acc[tile][nt] = __builtin_amdgcn_mfma_f32_16x16x32_bf16(av0, bfrag[nt][0], acc[tile][nt], 0, 0, 0);
            acc[tile][nt] = __builtin_amdgcn_mfma_f32_16x16x32_bf16(av1, bfrag[nt][1], acc[tile][nt], 0, 0, 0);
        }
    }

    // ---- epilogue ----
#pragma unroll
    for (int tile = 0; tile < 2; ++tile) {
        float tm[4][4];
#pragma unroll
        for (int nt = 0; nt < 4; ++nt)
#pragma unroll
            for (int r = 0; r < 4; ++r)
                tm[nt][r] = acc[tile][nt][r] + bias_l[nt];

#pragma unroll
        for (int r = 0; r < 4; ++r) {
            float p = tm[0][r] + tm[1][r] + tm[2][r] + tm[3][r];
#pragma unroll
            for (int off = 1; off < 16; off <<= 1) p += __shfl_xor(p, off, 64);
            float mean = p * (1.0f / 64.0f);
            float vs = 0.f;
#pragma unroll
            for (int nt = 0; nt < 4; ++nt) {
                float d = tm[nt][r] - mean;
                vs = fmaf(d, d, vs);
            }
#pragma unroll
            for (int off = 1; off < 16; off <<= 1) vs += __shfl_xor(vs, off, 64);
            float rstd = __frsqrt_rn(vs * (1.0f / 64.0f) + EPS_IN);

            int node = G0 + wv * 32 + tile * 16 + q * 4 + r;
            if (!BOUND || node < Ntot) {
                int base = node * 64 + c15;
                float av = 0.f;
                if (MODE == 3) av = auxs[node];
#pragma unroll
                for (int nt = 0; nt < 4; ++nt) {
                    float d = (tm[nt][r] - mean) * rstd;
                    if (MODE == 1) d += (float)auxv[base + nt * 16];
                    if (MODE == 3) d = fmaf(av, wi_e[nt], d + bi_e[nt]);
                    out[base + nt * 16] = (__bf16)celu1(d);
                }
            }
        }
    }
}

// ---------------------------------------------------------------------------
// 2x2 max pool (truncating), bf16 in/out, 4 channels per lane
// ---------------------------------------------------------------------------
template<int KK>
__global__ __launch_bounds__(256) void pool_kernel(
    const __bf16* __restrict__ xin, __bf16* __restrict__ out)
{
    constexpr int NIN = KK * KK;
    constexpr int KH = KK / 2;
    constexpr int P = KH * KH;
    int e = blockIdx.x * 256 + threadIdx.x;
    int c = (e & 15) * 4;
    int np = e >> 4;
    int b = np / P, p = np - b * P;
    int pi = p / KH, pj = p - pi * KH;
    int basei = (b * NIN + (2 * pi) * KK + 2 * pj) * 64 + c;
    bf16x4 v0 = *(const bf16x4*)(xin + basei);
    bf16x4 v1 = *(const bf16x4*)(xin + basei + 64);
    bf16x4 v2 = *(const bf16x4*)(xin + basei + KK * 64);
    bf16x4 v3 = *(const bf16x4*)(xin + basei + KK * 64 + 64);
    bf16x4 o;
#pragma unroll
    for (int z = 0; z < 4; ++z) {
        float mv = fmaxf(fmaxf((float)v0[z], (float)v1[z]),
                         fmaxf((float)v2[z], (float)v3[z]));
        o[z] = (__bf16)mv;
    }
    *(bf16x4*)(out + np * 64 + c) = o;
}

// ---------------------------------------------------------------------------
// Merged partial Gram: z<6 -> W1 chunk z; z>=6 -> W2 chunk z-6.
// ---------------------------------------------------------------------------
__global__ __launch_bounds__(256) void gram_kernel(
    const float* __restrict__ W1, const float* __restrict__ W2,
    float* __restrict__ Gp1, float* __restrict__ Gp2)
{
    const float* W; float* G; int K, kc, s;
    if (blockIdx.z < 6) { W = W1; K = 2304; kc = 384; s = blockIdx.z;     G = Gp1 + s * 65536; }
    else               { W = W2; K = 256;  kc = 128; s = blockIdx.z - 6; G = Gp2 + s * 65536; }

    __shared__ float As[32][33];
    __shared__ float Bs[32][33];
    int ti = blockIdx.x * 32;
    int tj = blockIdx.y * 32;
    int k0s = s * kc;
    int tx = threadIdx.x & 15, ty = threadIdx.x >> 4;
    float a00 = 0.f, a01 = 0.f, a10 = 0.f, a11 = 0.f;
    for (int k0 = k0s; k0 < k0s + kc; k0 += 32) {
        for (int l = threadIdx.x; l < 1024; l += 256) {
            int r = l >> 5, cc = l & 31;
            As[r][cc] = W[(ti + r) * K + k0 + cc];
            Bs[r][cc] = W[(tj + r) * K + k0 + cc];
        }
        __syncthreads();
#pragma unroll
        for (int kk = 0; kk < 32; ++kk) {
            float a0 = As[ty][kk],      a1 = As[ty + 16][kk];
            float b0 = Bs[tx][kk],      b1 = Bs[tx + 16][kk];
            a00 = fmaf(a0, b0, a00); a01 = fmaf(a0, b1, a01);
            a10 = fmaf(a1, b0, a10); a11 = fmaf(a1, b1, a11);
        }
        __syncthreads();
    }
    G[(ti + ty) * 256 + tj + tx]           = a00;
    G[(ti + ty) * 256 + tj + tx + 16]      = a01;
    G[(ti + ty + 16) * 256 + tj + tx]      = a10;
    G[(ti + ty + 16) * 256 + tj + tx + 16] = a11;
}

// ---------------------------------------------------------------------------
// Power iteration on symmetric G (256x256), partial-sum G inputs, deferred
// normalization. G row-chunk held as f32x4 g4[16] (vector regs — the
// allocator keeps ext_vector values in VGPRs where scalar arrays spill).
// ---------------------------------------------------------------------------
__global__ __launch_bounds__(1024) void power_kernel(
    const float* __restrict__ Gp1, const float* __restrict__ Gp2,
    float* __restrict__ sig)
{
    const float* Gp = (blockIdx.x == 0) ? Gp1 : Gp2;
    const int S = (blockIdx.x == 0) ? 6 : 2;
    __shared__ __align__(16) float u[256];
    __shared__ float red[1024];
    __shared__ float gu_s[256];
    int tid = threadIdx.x, i = tid & 255, q = tid >> 8;

    f32x4 g4[16];
#pragma unroll
    for (int m4 = 0; m4 < 16; ++m4) g4[m4] = (f32x4){0.f, 0.f, 0.f, 0.f};
    for (int s = 0; s < S; ++s) {
        const float* Gs = Gp + s * 65536 + i;
#pragma unroll
        for (int m4 = 0; m4 < 16; ++m4) {
            f32x4 t;
#pragma unroll
            for (int z = 0; z < 4; ++z)
                t[z] = Gs[(q * 64 + m4 * 4 + z) * 256];
            g4[m4] += t;
        }
    }

    if (tid < 256) u[tid] = 0.0625f;
    __syncthreads();

    for (int it = 0; it < 29; ++it) {
        float p = 0.f;
#pragma unroll
        for (int m4 = 0; m4 < 16; ++m4) {
            f32x4 uv = *(const f32x4*)(u + q * 64 + m4 * 4);
            p = fmaf(g4[m4][0], uv[0], p);
            p = fmaf(g4[m4][1], uv[1], p);
            p = fmaf(g4[m4][2], uv[2], p);
            p = fmaf(g4[m4][3], uv[3], p);
        }
        red[tid] = p;
        __syncthreads();
        if (tid < 256)
            u[tid] = (red[tid] + red[tid + 256] + red[tid + 512] + red[tid + 768]) * 0.5f;
        __syncthreads();
    }

    float p = 0.f;
#pragma unroll
    for (int m4 = 0; m4 < 16; ++m4) {
        f32x4 uv = *(const f32x4*)(u + q * 64 + m4 * 4);
        p = fmaf(g4[m4][0], uv[0], p);
        p = fmaf(g4[m4][1], uv[1], p);
        p = fmaf(g4[m4][2], uv[2], p);
        p = fmaf(g4[m4][3], uv[3], p);
    }
    red[tid] = p;
    __syncthreads();
    if (tid < 256)
        gu_s[tid] = red[tid] + red[tid + 256] + red[tid + 512] + red[tid + 768];
    __syncthreads();
    if (tid < 64) {
        float a = 0.f, bs = 0.f;
        for (int z = tid; z < 256; z += 64) {
            float v = gu_s[z];
            a = fmaf(v, v, a);
            bs = fmaf(u[z], v, bs);
        }
#pragma unroll
        for (int off = 32; off; off >>= 1) {
            a  += __shfl_xor(a, off, 64);
            bs += __shfl_xor(bs, off, 64);
        }
        if (tid == 0) sig[blockIdx.x] = sqrtf(a / bs);
    }
}

// ---------------------------------------------------------------------------
// Split-K linear partials (X is bf16) + epilogue
// ---------------------------------------------------------------------------
__global__ __launch_bounds__(256) void linear_part(
    const __bf16* __restrict__ X, const float* __restrict__ Wt,
    float* __restrict__ part, int K, int kchunk)
{
    __shared__ float wl[64 * 129];
    __shared__ float hl[16 * 128];
    int o0 = blockIdx.x * 64, b0 = blockIdx.y * 16;
    int s = blockIdx.z;
    int k0s = s * kchunk;
    int t = threadIdx.x, o = t & 63, br = t >> 6;
    float acc[4] = {0.f, 0.f, 0.f, 0.f};

    for (int k0 = k0s; k0 < k0s + kchunk; k0 += 128) {
        for (int l = t; l < 64 * 128; l += 256) {
            int r = l >> 7, cc = l & 127;
            wl[r * 129 + cc] = Wt[(o0 + r) * K + k0 + cc];
        }
        for (int l = t; l < 16 * 128; l += 256) {
            int r = l >> 7, cc = l & 127;
            hl[r * 128 + cc] = (float)X[(b0 + r) * K + k0 + cc];
        }
        __syncthreads();
        for (int kk = 0; kk < 128; ++kk) {
            float wv = wl[o * 129 + kk];
#pragma unroll
            for (int r = 0; r < 4; ++r)
                acc[r] = fmaf(hl[(br + (r << 2)) * 128 + kk], wv, acc[r]);
        }
        __syncthreads();
    }
#pragma unroll
    for (int r = 0; r < 4; ++r)
        part[(s * 64 + b0 + br + (r << 2)) * 256 + o0 + o] = acc[r];
}

__global__ __launch_bounds__(256) void linear_epi(
    const float* __restrict__ part, const float* __restrict__ bias,
    const float* __restrict__ sig, int sidx, int S,
    float* __restrict__ outf, __bf16* __restrict__ outb)
{
    int idx = blockIdx.x * 256 + threadIdx.x;
    float a = 0.f;
    for (int s = 0; s < S; ++s) a += part[s * 16384 + idx];
    int o = idx & 255;
    float v = celu1(a / sig[sidx] + bias[o]);
    if (outf) outf[idx] = v;
    if (outb) outb[idx] = (__bf16)v;
}

// ---------------------------------------------------------------------------
extern "C" void kernel_launch(void* const* d_in, const int* in_sizes, int n_in,
                              void* d_out, int out_size, void* d_ws, size_t ws_size,
                              hipStream_t stream)
{
    const float* x      = (const float*)d_in[0];
    const float* w_init = (const float*)d_in[1];
    const float* b_init = (const float*)d_in[2];
    const float* w11 = (const float*)d_in[3];  const float* b11 = (const float*)d_in[4];
    const float* w12 = (const float*)d_in[5];  const float* b12 = (const float*)d_in[6];
    const float* w21 = (const float*)d_in[7];  const float* b21 = (const float*)d_in[8];
    const float* w22 = (const float*)d_in[9];  const float* b22 = (const float*)d_in[10];
    const float* w31 = (const float*)d_in[11]; const float* b31 = (const float*)d_in[12];
    const float* w32 = (const float*)d_in[13]; const float* b32 = (const float*)d_in[14];
    const float* lw1 = (const float*)d_in[15]; const float* lb1 = (const float*)d_in[16];
    const float* lw2 = (const float*)d_in[17]; const float* lb2 = (const float*)d_in[18];
    float* out = (float*)d_out;

    char* ws = (char*)d_ws;
    const size_t SZ_BIG = (size_t)BATCH * N1 * 64 * sizeof(float);   // 40,960,000 B
    __bf16* A    = (__bf16*)ws;
    __bf16* Bb   = (__bf16*)(ws + SZ_BIG);
    __bf16* Cb   = (__bf16*)(ws + 2 * SZ_BIG);
    float*  agg  = (float*)(ws + 3 * SZ_BIG);          // 640 KB
    float*  agg2 = agg + BATCH * N1;                   // 640 KB
    float* Gp1   = agg2 + BATCH * N1;    // 6 * 65536
    float* Gp2   = Gp1 + 6 * 65536;      // 2 * 65536
    float* sg    = Gp2 + 2 * 65536;      // 2 (+pad)
    float* part1 = sg + 16;              // 6 * 16384
    float* part2 = part1 + 6 * 16384;    // 2 * 16384
    __bf16* H1b  = (__bf16*)(part2 + 2 * 16384);   // 16384 bf16

    // Stage 0: scalar aggregate fields (h0 rank-1, never materialized)
    stencil_kernel<<<625, 256, 0, stream>>>(x, agg);
    stencil_kernel<<<625, 256, 0, stream>>>(agg, agg2);

    // Block 1 (k=50, 160000 nodes, exact grids)
    conv1_kernel<K1><<<1250, 256, 0, stream>>>(agg2, w_init, b_init, w11, b11, Bb);
    conv_kernel<K1, 3, false><<<1250, 256, 0, stream>>>(Bb, nullptr, agg, w_init, b_init, w12, b12, Cb, BATCH * N1);
    pool_kernel<K1><<<BATCH * N2 * 16 / 256, 256, 0, stream>>>(Cb, A);

    // Block 2 (k=25, 40000 nodes)
    conv_kernel<K2, 0, true><<<313, 256, 0, stream>>>(A,  nullptr, nullptr, nullptr, nullptr, w21, b21, Bb, BATCH * N2);
    conv_kernel<K2, 1, true><<<313, 256, 0, stream>>>(Bb, A,       nullptr, nullptr, nullptr, w22, b22, Cb, BATCH * N2);
    pool_kernel<K2><<<BATCH * N3 * 16 / 256, 256, 0, stream>>>(Cb, A);

    // Block 3 (k=12, 9216 nodes, exact)
    conv_kernel<K3, 0, false><<<72, 256, 0, stream>>>(A,  nullptr, nullptr, nullptr, nullptr, w31, b31, Bb, BATCH * N3);
    conv_kernel<K3, 1, false><<<72, 256, 0, stream>>>(Bb, A,       nullptr, nullptr, nullptr, w32, b32, Cb, BATCH * N3);
    pool_kernel<K3><<<BATCH * 36 * 16 / 256, 256, 0, stream>>>(Cb, A);
    // A now holds h [64, 36, 64] bf16 == flattened [64, 2304]

    // Spectral norms (gram partials; reduce folded into power)
    gram_kernel<<<dim3(8, 8, 8), 256, 0, stream>>>(lw1, lw2, Gp1, Gp2);
    power_kernel<<<2, 1024, 0, stream>>>(Gp1, Gp2, sg);

    // Final linears with CELU (split-K partials + epilogue)
    linear_part<<<dim3(4, 4, 6), 256, 0, stream>>>(A,   lw1, part1, 2304, 384);
    linear_epi<<<64, 256, 0, stream>>>(part1, lb1, sg, 0, 6, nullptr, H1b);
    linear_part<<<dim3(4, 4, 2), 256, 0, stream>>>(H1b, lw2, part2, 256, 128);
    linear_epi<<<64, 256, 0, stream>>>(part2, lb2, sg, 1, 2, out, nullptr);
}